// Round 15
// baseline (1513.149 us; speedup 1.0000x reference)
//
#include <hip/hip_runtime.h>

#define IN_CH 256
#define FH 200
#define FW 200
#define NPIX 40000
#define NA 3
#define NANCH 120000
#define KSEL 1000
#define KTOT 2304          // k = (kx*3+ky)*256 + ic  (Eigen ColMajor NHWC patch order)
#define KC 288             // Eigen gebp kc: ((32768-384)/112) & ~7 = 288
#define NPANEL 8           // 2304 / 288
#define NTILE 9            // 288 / 32
#define NCAND 4096
#define NBIN 65536
#define NMS_T 0.7f
#define MIN_SIZE 0.001f

typedef unsigned int u32;
typedef unsigned long long u64;

__device__ __forceinline__ u32 mono32(float f) {
    u32 u = __float_as_uint(f);
    return (u & 0x80000000u) ? ~u : (u | 0x80000000u);
}

// ---------------- K0: transpose weights to ColMajor-tap order:
// wt[oc][(kx*3+ky)*256 + ic] = conv_w[oc][ic*9 + ky*3+kx]
__global__ __launch_bounds__(256) void k_transpose(const float* __restrict__ conv_w,
                                                   float* __restrict__ wt) {
    int idx = blockIdx.x * 256 + threadIdx.x;
    if (idx >= IN_CH * KTOT) return;
    int oc = idx / KTOT;
    int k  = idx - oc * KTOT;
    int ic = k / 9;
    int rr = k - ic * 9;          // ky*3+kx (row-major tap in OIHW layout)
    int ky = rr / 3;
    int kx = rr - ky * 3;
    int rc = kx * 3 + ky;         // ColMajor tap index (ky fastest)
    wt[oc * KTOT + rc * 256 + ic] = conv_w[idx];
}

// ---------------- K1: 3x3 conv emulating Eigen ColMajor contraction:
// k = (kx*3+ky)*256 + ic ascending (ic fastest, then ky, then kx);
// per kc=288 panel: fresh partial, sequential FMA chain; f32 '+=' per panel.
// Then f32 bias + relu -> t[256][40000].
__global__ __launch_bounds__(256) void k_conv(const float* __restrict__ feat,
                                              const float* __restrict__ wt,
                                              const float* __restrict__ bias,
                                              float* __restrict__ t) {
    __shared__ float As[32][64];   // [klocal][oc]
    __shared__ float Bs[32][64];   // [klocal][p]
    const int tid    = threadIdx.x;
    const int pbase  = blockIdx.x * 64;
    const int ocbase = blockIdx.y * 64;

    const int plocal = tid & 63;
    const int kgrp   = tid >> 6;     // 0..3
    const int p      = pbase + plocal;
    const int y      = p / FW;
    const int x      = p - y * FW;

    const int a_oc = tid >> 2;       // 0..63
    const int a_kq = tid & 3;        // 0..3

    const int ty = tid >> 4;         // 0..15 -> oc quad
    const int tx = tid & 15;         // 0..15 -> p quad

    float acc[4][4];
#pragma unroll
    for (int i = 0; i < 4; i++)
#pragma unroll
        for (int j = 0; j < 4; j++) acc[i][j] = 0.0f;

    for (int panel = 0; panel < NPANEL; panel++) {
        float part[4][4];
#pragma unroll
        for (int i = 0; i < 4; i++)
#pragma unroll
            for (int j = 0; j < 4; j++) part[i][j] = 0.0f;

        for (int tile = 0; tile < NTILE; tile++) {
            const int kbase = panel * KC + tile * 32;
            // B-staging: each (kgrp,i) is one k; ColMajor tap decode kx=r/3, ky=r%3
#pragma unroll
            for (int i = 0; i < 8; i++) {
                const int k  = kbase + kgrp * 8 + i;
                const int r  = k >> 8;           // tap (k = r*256+ic), r = kx*3+ky
                const int ic = k & 255;
                const int kx = r / 3;
                const int ky = r - kx * 3;
                const int yy = y + ky - 1, xx = x + kx - 1;
                const bool okp = ((unsigned)yy < (unsigned)FH) && ((unsigned)xx < (unsigned)FW);
                float v = okp ? feat[(size_t)ic * NPIX + yy * FW + xx] : 0.0f; // fmaf(w,0,acc)==acc
                Bs[kgrp * 8 + i][plocal] = v;
            }
            // A-staging: wt is k-contiguous in ColMajor-tap order
            const float* aptr = wt + (size_t)(ocbase + a_oc) * KTOT + kbase + a_kq * 8;
            float4 a0 = *(const float4*)aptr;
            float4 a1 = *(const float4*)(aptr + 4);
            As[a_kq * 8 + 0][a_oc] = a0.x;
            As[a_kq * 8 + 1][a_oc] = a0.y;
            As[a_kq * 8 + 2][a_oc] = a0.z;
            As[a_kq * 8 + 3][a_oc] = a0.w;
            As[a_kq * 8 + 4][a_oc] = a1.x;
            As[a_kq * 8 + 5][a_oc] = a1.y;
            As[a_kq * 8 + 6][a_oc] = a1.z;
            As[a_kq * 8 + 7][a_oc] = a1.w;
            __syncthreads();
#pragma unroll
            for (int kk = 0; kk < 32; kk++) {
                float4 av = *(const float4*)&As[kk][ty * 4];
                float4 bv = *(const float4*)&Bs[kk][tx * 4];
                part[0][0] = fmaf(av.x, bv.x, part[0][0]);
                part[0][1] = fmaf(av.x, bv.y, part[0][1]);
                part[0][2] = fmaf(av.x, bv.z, part[0][2]);
                part[0][3] = fmaf(av.x, bv.w, part[0][3]);
                part[1][0] = fmaf(av.y, bv.x, part[1][0]);
                part[1][1] = fmaf(av.y, bv.y, part[1][1]);
                part[1][2] = fmaf(av.y, bv.z, part[1][2]);
                part[1][3] = fmaf(av.y, bv.w, part[1][3]);
                part[2][0] = fmaf(av.z, bv.x, part[2][0]);
                part[2][1] = fmaf(av.z, bv.y, part[2][1]);
                part[2][2] = fmaf(av.z, bv.z, part[2][2]);
                part[2][3] = fmaf(av.z, bv.w, part[2][3]);
                part[3][0] = fmaf(av.w, bv.x, part[3][0]);
                part[3][1] = fmaf(av.w, bv.y, part[3][1]);
                part[3][2] = fmaf(av.w, bv.z, part[3][2]);
                part[3][3] = fmaf(av.w, bv.w, part[3][3]);
            }
            __syncthreads();
        }
        // gebp panel boundary: C += panel result (one f32 rounding per panel)
#pragma unroll
        for (int i = 0; i < 4; i++)
#pragma unroll
            for (int j = 0; j < 4; j++)
                acc[i][j] = __fadd_rn(acc[i][j], part[i][j]);
    }

#pragma unroll
    for (int i = 0; i < 4; i++) {
        float bb = bias[ocbase + ty * 4 + i];
#pragma unroll
        for (int j = 0; j < 4; j++) {
            float v = __fadd_rn(acc[i][j], bb);   // f32 bias add (op boundary)
            v = fmaxf(v, 0.0f);                   // relu
            t[(size_t)(ocbase + ty * 4 + i) * NPIX + pbase + tx * 4 + j] = v;
        }
    }
}

// ---------------- K2: 1x1 heads — k=256 < kc: single-panel sequential FMA chain
__global__ __launch_bounds__(256) void k_heads(const float* __restrict__ t,
                                               const float* __restrict__ cls_w,
                                               const float* __restrict__ cls_b,
                                               const float* __restrict__ bbox_w,
                                               const float* __restrict__ bbox_b,
                                               float* __restrict__ scores,
                                               float* __restrict__ dbuf,
                                               u32* __restrict__ hist) {
    __shared__ float wl[15][256];
    __shared__ float bl[15];
    const int tid = threadIdx.x;
    for (int i = tid; i < 3 * 256; i += 256) wl[i >> 8][i & 255] = cls_w[i];
    for (int i = tid; i < 12 * 256; i += 256) wl[3 + (i >> 8)][i & 255] = bbox_w[i];
    if (tid < 15) bl[tid] = (tid < 3) ? cls_b[tid] : bbox_b[tid - 3];
    __syncthreads();

    const int p = blockIdx.x * 256 + tid;
    if (p >= NPIX) return;

    float accs[15];
#pragma unroll
    for (int i = 0; i < 15; i++) accs[i] = 0.0f;

    for (int ic = 0; ic < 256; ic++) {
        float v = t[(size_t)ic * NPIX + p];
#pragma unroll
        for (int rr = 0; rr < 15; rr++) {
            accs[rr] = fmaf(v, wl[rr][ic], accs[rr]);   // strict chain, ic ascending
        }
    }

#pragma unroll
    for (int a = 0; a < 3; a++) {
        float s = __fadd_rn(accs[a], bl[a]);
        scores[p * 3 + a] = s;
        atomicAdd(&hist[mono32(s) >> 16], 1u);
    }
#pragma unroll
    for (int c = 0; c < 12; c++) {
        dbuf[(size_t)c * NPIX + p] = __fadd_rn(accs[3 + c], bl[3 + c]);
    }
}

// ---------------- K3: cutoff bin b = smallest-from-top bin16 with cum count >= KSEL
__global__ __launch_bounds__(256) void k_scan(const u32* __restrict__ hist,
                                              int* __restrict__ ctrl) {
    __shared__ u32 part[256];
    const int t = threadIdx.x;
    u32 s = 0;
    for (int i = 0; i < 256; i++) s += hist[t * 256 + i];
    part[t] = s;
    __syncthreads();
    if (t == 0) {
        u32 cum = 0;
        int b = 0;
        bool found = false;
        for (int c = 255; c >= 0 && !found; c--) {
            if (cum + part[c] >= (u32)KSEL) {
                for (int i = 255; i >= 0; i--) {
                    cum += hist[c * 256 + i];
                    if (cum >= (u32)KSEL) { b = c * 256 + i; found = true; break; }
                }
            } else {
                cum += part[c];
            }
        }
        ctrl[1] = b;
    }
}

// ---------------- K4: compact candidates: key = (mono32(score) << 32) | ~idx
__global__ __launch_bounds__(256) void k_compact(const float* __restrict__ scores,
                                                 int* __restrict__ ctrl,
                                                 u64* __restrict__ cand) {
    int i = blockIdx.x * 256 + threadIdx.x;
    if (i >= NANCH) return;
    u32 m = mono32(scores[i]);
    if ((int)(m >> 16) >= ctrl[1]) {
        int pos = atomicAdd(&ctrl[0], 1);
        if (pos < NCAND)
            cand[pos] = ((u64)m << 32) | (u32)(~(u32)i);
    }
}

// ---------------- K5: bitonic sort desc, top-1000, f32 decode + clip + validity
__global__ __launch_bounds__(1024) void k_sortsel(const u64* __restrict__ cand,
                                                  const float* __restrict__ dbuf,
                                                  const float* __restrict__ scores,
                                                  const int* __restrict__ ihp,
                                                  const int* __restrict__ iwp,
                                                  float* __restrict__ selbox,
                                                  float* __restrict__ selscore,
                                                  int* __restrict__ selvalid) {
    __shared__ u64 key[NCAND];
    const int tid = threadIdx.x;
    for (int i = tid; i < NCAND; i += 1024) key[i] = cand[i];
    __syncthreads();
    for (int k = 2; k <= NCAND; k <<= 1) {
        for (int j = k >> 1; j > 0; j >>= 1) {
            for (int i = tid; i < NCAND; i += 1024) {
                int l = i ^ j;
                if (l > i) {
                    u64 a = key[i], b = key[l];
                    bool sw = ((i & k) == 0) ? (a < b) : (a > b);
                    if (sw) { key[i] = b; key[l] = a; }
                }
            }
            __syncthreads();
        }
    }
    if (tid < KSEL) {
        u32 idx = ~(u32)(key[tid] & 0xFFFFFFFFull);
        int p = idx / 3, a = idx - 3 * p;
        int y = p / FW, x = p - y * FW;
        const int iw = *iwp, ih = *ihp;
        const float swf = (float)(iw / FW), shf = (float)(ih / FH);
        const float aw[3] = {46.f, 32.f, 22.f};
        const float ah[3] = {22.f, 32.f, 46.f};
        float dx = dbuf[(size_t)(a * 4 + 0) * NPIX + p];
        float dy = dbuf[(size_t)(a * 4 + 1) * NPIX + p];
        float dw = dbuf[(size_t)(a * 4 + 2) * NPIX + p];
        float dh = dbuf[(size_t)(a * 4 + 3) * NPIX + p];
        dw = fminf(dw, 4.135166556742356f);
        dh = fminf(dh, 4.135166556742356f);
        float cx = __fmul_rn((float)x, swf), cy = __fmul_rn((float)y, shf);
        float pcx = __fadd_rn(__fmul_rn(dx, aw[a]), cx);
        float pcy = __fadd_rn(__fmul_rn(dy, ah[a]), cy);
        float ew = (float)exp((double)dw);
        float eh = (float)exp((double)dh);
        float pw = __fmul_rn(ew, aw[a]);
        float ph = __fmul_rn(eh, ah[a]);
        float hw = __fmul_rn(0.5f, pw), hh = __fmul_rn(0.5f, ph);
        float x1 = __fsub_rn(pcx, hw), y1 = __fsub_rn(pcy, hh);
        float x2 = __fadd_rn(pcx, hw), y2 = __fadd_rn(pcy, hh);
        float W = (float)iw, H = (float)ih;
        x1 = fminf(fmaxf(x1, 0.0f), W);
        y1 = fminf(fmaxf(y1, 0.0f), H);
        x2 = fminf(fmaxf(x2, 0.0f), W);
        y2 = fminf(fmaxf(y2, 0.0f), H);
        bool isv = (__fsub_rn(x2, x1) >= MIN_SIZE) && (__fsub_rn(y2, y1) >= MIN_SIZE);
        selbox[tid * 4 + 0] = x1;
        selbox[tid * 4 + 1] = y1;
        selbox[tid * 4 + 2] = x2;
        selbox[tid * 4 + 3] = y2;
        selscore[tid] = scores[idx];
        selvalid[tid] = isv ? 1 : 0;
    }
}

// ---------------- K6: sequential NMS in pure f32 (mirror of reference fori_loop)
__global__ __launch_bounds__(256) void k_nms(const float* __restrict__ selbox,
                                             const float* __restrict__ selscore,
                                             const int* __restrict__ selvalid,
                                             float* __restrict__ out) {
    __shared__ float bx[KSEL][4];
    __shared__ float area[KSEL];
    __shared__ int kp[KSEL];
    volatile int* vkp = kp;
    const int tid = threadIdx.x;
    for (int r = tid; r < KSEL; r += 256) {
        float x1 = selbox[r * 4 + 0], y1 = selbox[r * 4 + 1];
        float x2 = selbox[r * 4 + 2], y2 = selbox[r * 4 + 3];
        bx[r][0] = x1; bx[r][1] = y1; bx[r][2] = x2; bx[r][3] = y2;
        area[r] = __fmul_rn(__fsub_rn(x2, x1), __fsub_rn(y2, y1));
        kp[r] = selvalid[r];
    }
    __syncthreads();

    for (int i = 0; i < KSEL - 1; i++) {
        if (vkp[i]) {   // uniform branch
            float x1 = bx[i][0], y1 = bx[i][1], x2 = bx[i][2], y2 = bx[i][3];
            float ai = area[i];
#pragma unroll
            for (int c = 0; c < 4; c++) {
                int j = c * 256 + tid;
                if (j > i && j < KSEL && vkp[j]) {
                    float xl = fmaxf(x1, bx[j][0]), yt = fmaxf(y1, bx[j][1]);
                    float xr = fminf(x2, bx[j][2]), yb = fminf(y2, bx[j][3]);
                    float inter = __fmul_rn(fmaxf(__fsub_rn(xr, xl), 0.0f),
                                            fmaxf(__fsub_rn(yb, yt), 0.0f));
                    float un = __fsub_rn(__fadd_rn(ai, area[j]), inter);
                    float iou = __fdiv_rn(inter, __fadd_rn(un, 1e-8f));
                    if (iou > NMS_T) vkp[j] = 0;
                }
            }
            __syncthreads();
        }
    }

    for (int r = tid; r < KSEL; r += 256) {
        bool kb = kp[r] != 0;
        out[r * 5 + 0] = kb ? bx[r][0] : 0.0f;
        out[r * 5 + 1] = kb ? bx[r][1] : 0.0f;
        out[r * 5 + 2] = kb ? bx[r][2] : 0.0f;
        out[r * 5 + 3] = kb ? bx[r][3] : 0.0f;
        out[r * 5 + 4] = kb ? selscore[r] : 0.0f;
        out[5000 + r] = kb ? 1.0f : 0.0f;
    }
}

static inline size_t align256(size_t x) { return (x + 255) & ~(size_t)255; }

extern "C" void kernel_launch(void* const* d_in, const int* in_sizes, int n_in,
                              void* d_out, int out_size, void* d_ws, size_t ws_size,
                              hipStream_t stream) {
    const float* feat   = (const float*)d_in[0];
    const float* conv_w = (const float*)d_in[1];
    const float* conv_b = (const float*)d_in[2];
    const float* cls_w  = (const float*)d_in[3];
    const float* cls_b  = (const float*)d_in[4];
    const float* bbox_w = (const float*)d_in[5];
    const float* bbox_b = (const float*)d_in[6];
    const int* ihp      = (const int*)d_in[7];
    const int* iwp      = (const int*)d_in[8];
    float* out = (float*)d_out;

    char* ws = (char*)d_ws;
    size_t off = 0;
    float* wt = (float*)(ws + off);         off += align256((size_t)IN_CH * KTOT * 4);
    float* t  = (float*)(ws + off);         off += align256((size_t)IN_CH * NPIX * 4);
    float* scores = (float*)(ws + off);     off += align256((size_t)NANCH * 4);
    float* dbuf = (float*)(ws + off);       off += align256((size_t)12 * NPIX * 4);
    u32* hist = (u32*)(ws + off);           size_t z0 = off; off += align256((size_t)NBIN * 4);
    int* ctrl = (int*)(ws + off);           off += 256;
    u64* cand = (u64*)(ws + off);           off += (size_t)NCAND * 8;
    size_t zlen = off - z0;
    off = align256(off);
    float* selbox = (float*)(ws + off);     off += align256((size_t)KSEL * 4 * 4);
    float* selscore = (float*)(ws + off);   off += align256((size_t)KSEL * 4);
    int* selvalid = (int*)(ws + off);       off += align256((size_t)KSEL * 4);

    hipMemsetAsync(ws + z0, 0, zlen, stream);   // hist + ctrl + cand

    k_transpose<<<(IN_CH * KTOT + 255) / 256, 256, 0, stream>>>(conv_w, wt);
    k_conv<<<dim3(NPIX / 64, IN_CH / 64), 256, 0, stream>>>(feat, wt, conv_b, t);
    k_heads<<<(NPIX + 255) / 256, 256, 0, stream>>>(t, cls_w, cls_b, bbox_w, bbox_b,
                                                    scores, dbuf, hist);
    k_scan<<<1, 256, 0, stream>>>(hist, ctrl);
    k_compact<<<(NANCH + 255) / 256, 256, 0, stream>>>(scores, ctrl, cand);
    k_sortsel<<<1, 1024, 0, stream>>>(cand, dbuf, scores, ihp, iwp,
                                      selbox, selscore, selvalid);
    k_nms<<<1, 256, 0, stream>>>(selbox, selscore, selvalid, out);
}

// Round 16
// 1025.422 us; speedup vs baseline: 1.4756x; 1.4756x over previous
//
#include <hip/hip_runtime.h>

#define IN_CH 256
#define FH 200
#define FW 200
#define NPIX 40000
#define NA 3
#define NANCH 120000
#define KSEL 1000
#define KTOT 2304          // k = (kx*3+ky)*256 + ic  (Eigen ColMajor NHWC patch order)
#define KC 288             // Eigen gebp kc panel — DO NOT CHANGE (bit-exactness)
#define NPANEL 8           // 2304 / 288
#define NTILE 9            // 288 / 32
#define NCAND 4096
#define NBIN 65536
#define NMS_T 0.7f
#define MIN_SIZE 0.001f

typedef unsigned int u32;
typedef unsigned long long u64;

__device__ __forceinline__ u32 mono32(float f) {
    u32 u = __float_as_uint(f);
    return (u & 0x80000000u) ? ~u : (u | 0x80000000u);
}

// ---------------- K0: transpose weights to ColMajor-tap order:
// wt[oc][(kx*3+ky)*256 + ic] = conv_w[oc][ic*9 + ky*3+kx]
__global__ __launch_bounds__(256) void k_transpose(const float* __restrict__ conv_w,
                                                   float* __restrict__ wt) {
    int idx = blockIdx.x * 256 + threadIdx.x;
    if (idx >= IN_CH * KTOT) return;
    int oc = idx / KTOT;
    int k  = idx - oc * KTOT;
    int ic = k / 9;
    int rr = k - ic * 9;          // ky*3+kx (row-major tap in OIHW layout)
    int ky = rr / 3;
    int kx = rr - ky * 3;
    int rc = kx * 3 + ky;         // ColMajor tap index (ky fastest)
    wt[oc * KTOT + rc * 256 + ic] = conv_w[idx];
}

// ---------------- K1: 3x3 conv, Eigen ColMajor contraction, kc=288 panels.
// NUMERICS LOCKED: per output element, sequential FMA chain in k ascending
// within each 288-panel, one f32 += per panel boundary. (Bit-exact vs ref.)
// Perf: 128oc x 64px tile, 8x4 microtile, chunk-uniform staging addresses.
__global__ __launch_bounds__(256) void k_conv(const float* __restrict__ feat,
                                              const float* __restrict__ wt,
                                              const float* __restrict__ bias,
                                              float* __restrict__ t) {
    __shared__ float As[32][128];   // [klocal][oc]   16 KB
    __shared__ float Bs[32][64];    // [klocal][px]    8 KB
    const int tid    = threadIdx.x;
    const int pbase  = blockIdx.x * 64;
    const int ocbase = blockIdx.y * 128;

    // B-staging mapping: 32 rows x 64 px, 8 rows/thread
    const int plocal = tid & 63;
    const int kgrp   = tid >> 6;     // 0..3 -> rows kgrp*8..+7
    const int p      = pbase + plocal;
    const int y      = p / FW;
    const int x      = p - y * FW;

    // A-staging mapping: 32 rows x 128 oc, 16 elems/thread (4x float4)
    const int a_oc   = tid >> 1;     // 0..127
    const int a_half = tid & 1;      // rows 0-15 or 16-31

    // compute mapping: 8 oc x 4 px per thread
    const int ty = tid >> 4;         // 0..15 -> oc octet
    const int tx = tid & 15;         // 0..15 -> px quad

    float acc[8][4];
#pragma unroll
    for (int i = 0; i < 8; i++)
#pragma unroll
        for (int j = 0; j < 4; j++) acc[i][j] = 0.0f;

    for (int panel = 0; panel < NPANEL; panel++) {
        float part[8][4];
#pragma unroll
        for (int i = 0; i < 8; i++)
#pragma unroll
            for (int j = 0; j < 4; j++) part[i][j] = 0.0f;

        for (int tile = 0; tile < NTILE; tile++) {
            const int kbase = panel * KC + tile * 32;
            // 32-chunks never cross a 256-boundary -> tap r uniform per chunk
            const int r      = kbase >> 8;        // r = kx*3+ky (ColMajor)
            const int icbase = kbase & 255;
            const int kx = r / 3;
            const int ky = r - kx * 3;
            const int yy = y + ky - 1, xx = x + kx - 1;
            const bool okp = ((unsigned)yy < (unsigned)FH) && ((unsigned)xx < (unsigned)FW);
            const int soff = okp ? (yy * FW + xx) : 0;
            const float* fptr = feat + (size_t)(icbase + kgrp * 8) * NPIX + soff;
#pragma unroll
            for (int i = 0; i < 8; i++) {
                float v = okp ? fptr[i * NPIX] : 0.0f;   // fmaf(w,0,acc)==acc exactly
                Bs[kgrp * 8 + i][plocal] = v;
            }
            const float* aptr = wt + (size_t)(ocbase + a_oc) * KTOT + kbase + a_half * 16;
#pragma unroll
            for (int q = 0; q < 4; q++) {
                float4 av = *(const float4*)(aptr + q * 4);
                As[a_half * 16 + q * 4 + 0][a_oc] = av.x;
                As[a_half * 16 + q * 4 + 1][a_oc] = av.y;
                As[a_half * 16 + q * 4 + 2][a_oc] = av.z;
                As[a_half * 16 + q * 4 + 3][a_oc] = av.w;
            }
            __syncthreads();
#pragma unroll
            for (int kk = 0; kk < 32; kk++) {
                float4 a0 = *(const float4*)&As[kk][ty * 8];
                float4 a1 = *(const float4*)&As[kk][ty * 8 + 4];
                float4 bv = *(const float4*)&Bs[kk][tx * 4];
                part[0][0] = fmaf(a0.x, bv.x, part[0][0]);
                part[0][1] = fmaf(a0.x, bv.y, part[0][1]);
                part[0][2] = fmaf(a0.x, bv.z, part[0][2]);
                part[0][3] = fmaf(a0.x, bv.w, part[0][3]);
                part[1][0] = fmaf(a0.y, bv.x, part[1][0]);
                part[1][1] = fmaf(a0.y, bv.y, part[1][1]);
                part[1][2] = fmaf(a0.y, bv.z, part[1][2]);
                part[1][3] = fmaf(a0.y, bv.w, part[1][3]);
                part[2][0] = fmaf(a0.z, bv.x, part[2][0]);
                part[2][1] = fmaf(a0.z, bv.y, part[2][1]);
                part[2][2] = fmaf(a0.z, bv.z, part[2][2]);
                part[2][3] = fmaf(a0.z, bv.w, part[2][3]);
                part[3][0] = fmaf(a0.w, bv.x, part[3][0]);
                part[3][1] = fmaf(a0.w, bv.y, part[3][1]);
                part[3][2] = fmaf(a0.w, bv.z, part[3][2]);
                part[3][3] = fmaf(a0.w, bv.w, part[3][3]);
                part[4][0] = fmaf(a1.x, bv.x, part[4][0]);
                part[4][1] = fmaf(a1.x, bv.y, part[4][1]);
                part[4][2] = fmaf(a1.x, bv.z, part[4][2]);
                part[4][3] = fmaf(a1.x, bv.w, part[4][3]);
                part[5][0] = fmaf(a1.y, bv.x, part[5][0]);
                part[5][1] = fmaf(a1.y, bv.y, part[5][1]);
                part[5][2] = fmaf(a1.y, bv.z, part[5][2]);
                part[5][3] = fmaf(a1.y, bv.w, part[5][3]);
                part[6][0] = fmaf(a1.z, bv.x, part[6][0]);
                part[6][1] = fmaf(a1.z, bv.y, part[6][1]);
                part[6][2] = fmaf(a1.z, bv.z, part[6][2]);
                part[6][3] = fmaf(a1.z, bv.w, part[6][3]);
                part[7][0] = fmaf(a1.w, bv.x, part[7][0]);
                part[7][1] = fmaf(a1.w, bv.y, part[7][1]);
                part[7][2] = fmaf(a1.w, bv.z, part[7][2]);
                part[7][3] = fmaf(a1.w, bv.w, part[7][3]);
            }
            __syncthreads();
        }
        // gebp panel boundary: C += panel result (one f32 rounding per panel)
#pragma unroll
        for (int i = 0; i < 8; i++)
#pragma unroll
            for (int j = 0; j < 4; j++)
                acc[i][j] = __fadd_rn(acc[i][j], part[i][j]);
    }

#pragma unroll
    for (int i = 0; i < 8; i++) {
        const int oc = ocbase + ty * 8 + i;
        float bb = bias[oc];
#pragma unroll
        for (int j = 0; j < 4; j++) {
            float v = __fadd_rn(acc[i][j], bb);   // f32 bias add (op boundary)
            v = fmaxf(v, 0.0f);                   // relu
            t[(size_t)oc * NPIX + pbase + tx * 4 + j] = v;
        }
    }
}

// ---------------- K2: 1x1 heads — k=256 single panel: sequential FMA chain (LOCKED)
__global__ __launch_bounds__(256) void k_heads(const float* __restrict__ t,
                                               const float* __restrict__ cls_w,
                                               const float* __restrict__ cls_b,
                                               const float* __restrict__ bbox_w,
                                               const float* __restrict__ bbox_b,
                                               float* __restrict__ scores,
                                               float* __restrict__ dbuf,
                                               u32* __restrict__ hist) {
    __shared__ float wl[15][256];
    __shared__ float bl[15];
    const int tid = threadIdx.x;
    for (int i = tid; i < 3 * 256; i += 256) wl[i >> 8][i & 255] = cls_w[i];
    for (int i = tid; i < 12 * 256; i += 256) wl[3 + (i >> 8)][i & 255] = bbox_w[i];
    if (tid < 15) bl[tid] = (tid < 3) ? cls_b[tid] : bbox_b[tid - 3];
    __syncthreads();

    const int p = blockIdx.x * 256 + tid;
    if (p >= NPIX) return;

    float accs[15];
#pragma unroll
    for (int i = 0; i < 15; i++) accs[i] = 0.0f;

    for (int ic = 0; ic < 256; ic++) {
        float v = t[(size_t)ic * NPIX + p];
#pragma unroll
        for (int rr = 0; rr < 15; rr++) {
            accs[rr] = fmaf(v, wl[rr][ic], accs[rr]);
        }
    }

#pragma unroll
    for (int a = 0; a < 3; a++) {
        float s = __fadd_rn(accs[a], bl[a]);
        scores[p * 3 + a] = s;
        atomicAdd(&hist[mono32(s) >> 16], 1u);
    }
#pragma unroll
    for (int c = 0; c < 12; c++) {
        dbuf[(size_t)c * NPIX + p] = __fadd_rn(accs[3 + c], bl[3 + c]);
    }
}

// ---------------- K3: cutoff bin — two-phase (coarse via LDS, fine bin staged to LDS)
__global__ __launch_bounds__(256) void k_scan(const u32* __restrict__ hist,
                                              int* __restrict__ ctrl) {
    __shared__ u32 part[256];
    __shared__ u32 fine[256];
    __shared__ int cstar;
    __shared__ u32 cumbase;
    const int t = threadIdx.x;
    u32 s = 0;
    for (int i = 0; i < 256; i++) s += hist[t * 256 + i];
    part[t] = s;
    __syncthreads();
    if (t == 0) {
        u32 cum = 0;
        int c = 255;
        for (; c > 0; c--) {
            if (cum + part[c] >= (u32)KSEL) break;
            cum += part[c];
        }
        cstar = c;
        cumbase = cum;
    }
    __syncthreads();
    const int c = cstar;
    fine[t] = hist[c * 256 + t];
    __syncthreads();
    if (t == 0) {
        u32 cum = cumbase;
        int b = 0;
        for (int i = 255; i >= 0; i--) {
            cum += fine[i];
            if (cum >= (u32)KSEL) { b = c * 256 + i; break; }
        }
        ctrl[1] = b;
    }
}

// ---------------- K4: compact candidates: key = (mono32(score) << 32) | ~idx
__global__ __launch_bounds__(256) void k_compact(const float* __restrict__ scores,
                                                 int* __restrict__ ctrl,
                                                 u64* __restrict__ cand) {
    int i = blockIdx.x * 256 + threadIdx.x;
    if (i >= NANCH) return;
    u32 m = mono32(scores[i]);
    if ((int)(m >> 16) >= ctrl[1]) {
        int pos = atomicAdd(&ctrl[0], 1);
        if (pos < NCAND)
            cand[pos] = ((u64)m << 32) | (u32)(~(u32)i);
    }
}

// ---------------- K5: bitonic sort desc, top-1000, f32 decode + clip + validity mask
__global__ __launch_bounds__(1024) void k_sortsel(const u64* __restrict__ cand,
                                                  const float* __restrict__ dbuf,
                                                  const float* __restrict__ scores,
                                                  const int* __restrict__ ihp,
                                                  const int* __restrict__ iwp,
                                                  float* __restrict__ selbox,
                                                  float* __restrict__ selscore,
                                                  u64* __restrict__ validmask) {
    __shared__ u64 key[NCAND];
    const int tid = threadIdx.x;
    for (int i = tid; i < NCAND; i += 1024) key[i] = cand[i];
    __syncthreads();
    for (int k = 2; k <= NCAND; k <<= 1) {
        for (int j = k >> 1; j > 0; j >>= 1) {
            for (int i = tid; i < NCAND; i += 1024) {
                int l = i ^ j;
                if (l > i) {
                    u64 a = key[i], b = key[l];
                    bool sw = ((i & k) == 0) ? (a < b) : (a > b);
                    if (sw) { key[i] = b; key[l] = a; }
                }
            }
            __syncthreads();
        }
    }
    bool isv = false;
    if (tid < KSEL) {
        u32 idx = ~(u32)(key[tid] & 0xFFFFFFFFull);
        int p = idx / 3, a = idx - 3 * p;
        int y = p / FW, x = p - y * FW;
        const int iw = *iwp, ih = *ihp;
        const float swf = (float)(iw / FW), shf = (float)(ih / FH);
        const float aw[3] = {46.f, 32.f, 22.f};
        const float ah[3] = {22.f, 32.f, 46.f};
        float dx = dbuf[(size_t)(a * 4 + 0) * NPIX + p];
        float dy = dbuf[(size_t)(a * 4 + 1) * NPIX + p];
        float dw = dbuf[(size_t)(a * 4 + 2) * NPIX + p];
        float dh = dbuf[(size_t)(a * 4 + 3) * NPIX + p];
        dw = fminf(dw, 4.135166556742356f);
        dh = fminf(dh, 4.135166556742356f);
        float cx = __fmul_rn((float)x, swf), cy = __fmul_rn((float)y, shf);
        float pcx = __fadd_rn(__fmul_rn(dx, aw[a]), cx);
        float pcy = __fadd_rn(__fmul_rn(dy, ah[a]), cy);
        float ew = (float)exp((double)dw);
        float eh = (float)exp((double)dh);
        float pw = __fmul_rn(ew, aw[a]);
        float ph = __fmul_rn(eh, ah[a]);
        float hw = __fmul_rn(0.5f, pw), hh = __fmul_rn(0.5f, ph);
        float x1 = __fsub_rn(pcx, hw), y1 = __fsub_rn(pcy, hh);
        float x2 = __fadd_rn(pcx, hw), y2 = __fadd_rn(pcy, hh);
        float W = (float)iw, H = (float)ih;
        x1 = fminf(fmaxf(x1, 0.0f), W);
        y1 = fminf(fmaxf(y1, 0.0f), H);
        x2 = fminf(fmaxf(x2, 0.0f), W);
        y2 = fminf(fmaxf(y2, 0.0f), H);
        isv = (__fsub_rn(x2, x1) >= MIN_SIZE) && (__fsub_rn(y2, y1) >= MIN_SIZE);
        selbox[tid * 4 + 0] = x1;
        selbox[tid * 4 + 1] = y1;
        selbox[tid * 4 + 2] = x2;
        selbox[tid * 4 + 3] = y2;
        selscore[tid] = scores[idx];
    }
    u64 m = __ballot(isv);
    if ((tid & 63) == 0) validmask[tid >> 6] = m;
}

// ---------------- K6a: parallel suppression bitmask sup[i][16 u64 words]
// Same __f*_rn IoU arithmetic as the reference comparison.
__global__ __launch_bounds__(256) void k_sup(const float* __restrict__ selbox,
                                             u64* __restrict__ sup) {
    const int i = blockIdx.x;
    const int tid = threadIdx.x;
    const float x1 = selbox[i * 4 + 0], y1 = selbox[i * 4 + 1];
    const float x2 = selbox[i * 4 + 2], y2 = selbox[i * 4 + 3];
    const float ai = __fmul_rn(__fsub_rn(x2, x1), __fsub_rn(y2, y1));
#pragma unroll
    for (int it = 0; it < 4; it++) {
        int j = it * 256 + tid;
        int jj = j < KSEL ? j : 0;
        float xj1 = selbox[jj * 4 + 0], yj1 = selbox[jj * 4 + 1];
        float xj2 = selbox[jj * 4 + 2], yj2 = selbox[jj * 4 + 3];
        float aj = __fmul_rn(__fsub_rn(xj2, xj1), __fsub_rn(yj2, yj1));
        float xl = fmaxf(x1, xj1), yt = fmaxf(y1, yj1);
        float xr = fminf(x2, xj2), yb = fminf(y2, yj2);
        float inter = __fmul_rn(fmaxf(__fsub_rn(xr, xl), 0.0f),
                                fmaxf(__fsub_rn(yb, yt), 0.0f));
        float un = __fsub_rn(__fadd_rn(ai, aj), inter);
        float iou = __fdiv_rn(inter, __fadd_rn(un, 1e-8f));
        bool pred = (j < KSEL) && (j > i) && (iou > NMS_T);
        u64 m = __ballot(pred);
        if ((tid & 63) == 0) sup[(size_t)i * 16 + it * 4 + (tid >> 6)] = m;
    }
}

// ---------------- K6b: sequential keep-scan (exact reference recurrence) + output
__global__ __launch_bounds__(256) void k_nms2(const u64* __restrict__ sup,
                                              const u64* __restrict__ validmask,
                                              const float* __restrict__ selbox,
                                              const float* __restrict__ selscore,
                                              float* __restrict__ out) {
    __shared__ u64 skeep[16];
    const int tid = threadIdx.x;
    if (tid < 16) skeep[tid] = validmask[tid];
    __syncthreads();
    if (tid < 64) {
        const int w = tid & 15;       // word index (lanes 16-63 mirror lanes 0-15)
        u64 kw = skeep[w];
        for (int i = 0; i < KSEL - 1; i++) {
            u64 row = sup[(size_t)i * 16 + w];   // kw-independent load -> pipelines
            u64 cur = __shfl(kw, i >> 6, 64);
            if ((cur >> (i & 63)) & 1ull) kw &= ~row;
        }
        if (tid < 16) skeep[tid] = kw;
    }
    __syncthreads();
    for (int r = tid; r < KSEL; r += 256) {
        bool kb = (skeep[r >> 6] >> (r & 63)) & 1ull;
        out[r * 5 + 0] = kb ? selbox[r * 4 + 0] : 0.0f;
        out[r * 5 + 1] = kb ? selbox[r * 4 + 1] : 0.0f;
        out[r * 5 + 2] = kb ? selbox[r * 4 + 2] : 0.0f;
        out[r * 5 + 3] = kb ? selbox[r * 4 + 3] : 0.0f;
        out[r * 5 + 4] = kb ? selscore[r] : 0.0f;
        out[5000 + r] = kb ? 1.0f : 0.0f;
    }
}

static inline size_t align256(size_t x) { return (x + 255) & ~(size_t)255; }

extern "C" void kernel_launch(void* const* d_in, const int* in_sizes, int n_in,
                              void* d_out, int out_size, void* d_ws, size_t ws_size,
                              hipStream_t stream) {
    const float* feat   = (const float*)d_in[0];
    const float* conv_w = (const float*)d_in[1];
    const float* conv_b = (const float*)d_in[2];
    const float* cls_w  = (const float*)d_in[3];
    const float* cls_b  = (const float*)d_in[4];
    const float* bbox_w = (const float*)d_in[5];
    const float* bbox_b = (const float*)d_in[6];
    const int* ihp      = (const int*)d_in[7];
    const int* iwp      = (const int*)d_in[8];
    float* out = (float*)d_out;

    char* ws = (char*)d_ws;
    size_t off = 0;
    float* wt = (float*)(ws + off);         off += align256((size_t)IN_CH * KTOT * 4);
    float* t  = (float*)(ws + off);         off += align256((size_t)IN_CH * NPIX * 4);
    float* scores = (float*)(ws + off);     off += align256((size_t)NANCH * 4);
    float* dbuf = (float*)(ws + off);       off += align256((size_t)12 * NPIX * 4);
    u32* hist = (u32*)(ws + off);           size_t z0 = off; off += align256((size_t)NBIN * 4);
    int* ctrl = (int*)(ws + off);           off += 256;
    u64* cand = (u64*)(ws + off);           off += (size_t)NCAND * 8;
    size_t zlen = off - z0;
    off = align256(off);
    float* selbox = (float*)(ws + off);     off += align256((size_t)KSEL * 4 * 4);
    float* selscore = (float*)(ws + off);   off += align256((size_t)KSEL * 4);
    u64* validmask = (u64*)(ws + off);      off += 256;
    u64* sup = (u64*)(ws + off);            off += align256((size_t)KSEL * 16 * 8);

    hipMemsetAsync(ws + z0, 0, zlen, stream);   // hist + ctrl + cand

    k_transpose<<<(IN_CH * KTOT + 255) / 256, 256, 0, stream>>>(conv_w, wt);
    k_conv<<<dim3(NPIX / 64, IN_CH / 128), 256, 0, stream>>>(feat, wt, conv_b, t);
    k_heads<<<(NPIX + 255) / 256, 256, 0, stream>>>(t, cls_w, cls_b, bbox_w, bbox_b,
                                                    scores, dbuf, hist);
    k_scan<<<1, 256, 0, stream>>>(hist, ctrl);
    k_compact<<<(NANCH + 255) / 256, 256, 0, stream>>>(scores, ctrl, cand);
    k_sortsel<<<1, 1024, 0, stream>>>(cand, dbuf, scores, ihp, iwp,
                                      selbox, selscore, validmask);
    k_sup<<<KSEL, 256, 0, stream>>>(selbox, sup);
    k_nms2<<<1, 256, 0, stream>>>(sup, validmask, selbox, selscore, out);
}